// Round 2
// baseline (236.997 us; speedup 1.0000x reference)
//
#include <hip/hip_runtime.h>

#define EDGES 4096
#define NNODES 256
// x: (256, 784), W: (256, 784, 128), b: (256, 128), edge_index: (2, 4096), ew: (4096)
// out: (256, 128)

typedef unsigned short u16;

// ---------------------------------------------------------------------------
// K1: c[n] = (1/N) * r[n], r^T = 1^T * Prod_{e=E-1..0}(I + w_e E_{t,s}).
// rho_e = 1 + sum_{e'>e, s_{e'}=t_e} w_{e'} rho_{e'}; r[n] = 1 + sum_{s_e=n} w_e rho_e.
// Neumann iteration, 5 passes (truncation error ~1e-7 after x16 amplification).
// Barrier-optimized: wave-0 shfl scan instead of 256-step Hillis-Steele.
// ---------------------------------------------------------------------------
__global__ __launch_bounds__(256) void k1_coeff(const int* __restrict__ ei,
                                                const float* __restrict__ ew,
                                                float* __restrict__ c_out) {
    __shared__ __align__(16) char smem[59648];
    float* w_q    = (float*)(smem);              // [0, 16K)      weight per sorted position
    u16*   s_e    = (u16*)  (smem + 16384);      // [16K, 24K)
    u16*   t_e    = (u16*)  (smem + 24576);      // [24K, 32K)
    float* rho    = (float*)(smem + 16384);      // [16K, 32K)    after P7
    u16*   id_q   = (u16*)  (smem + 32768);      // [32K, 40K)    sorted ids
    u16*   t_q    = (u16*)  (smem + 40960);      // [40K, 48K)
    float* sfx    = (float*)(smem + 32768);      // [32K, 48K)    after P7
    u16*   id_u   = (u16*)  (smem + 49152);      // [48K, 56K)
    u16*   start_q= (u16*)  (smem + 49152);      // aliases id_u (dead by then)
    int*   offs   = (int*)  (smem + 57344);      // 257 ints
    int*   fillc  = (int*)  (smem + 58372);      // 256 ints

    const int tid = threadIdx.x;

    // P0: load edges, zero counters
    for (int j = tid; j < EDGES; j += 256) {
        s_e[j] = (u16)ei[j];
        t_e[j] = (u16)ei[EDGES + j];
    }
    fillc[tid] = 0;
    __syncthreads();

    // P1: count by source
    for (int j = tid; j < EDGES; j += 256) atomicAdd(&fillc[s_e[j]], 1);
    __syncthreads();

    // P2: exclusive scan via wave-0 shfl (lane l owns buckets 4l..4l+3)
    if (tid < 64) {
        int b0 = tid * 4;
        int c0 = fillc[b0], c1 = fillc[b0 + 1], c2 = fillc[b0 + 2], c3 = fillc[b0 + 3];
        int s  = c0 + c1 + c2 + c3;
        int inc = s;
        #pragma unroll
        for (int d = 1; d < 64; d <<= 1) {
            int v = __shfl_up(inc, d);
            if (tid >= d) inc += v;
        }
        int excl = inc - s;
        offs[b0]     = excl;
        offs[b0 + 1] = excl + c0;
        offs[b0 + 2] = excl + c0 + c1;
        offs[b0 + 3] = excl + c0 + c1 + c2;
        if (tid == 63) offs[256] = inc;
    }
    __syncthreads();

    // P3: fill cursors = offs
    fillc[tid] = offs[tid];
    __syncthreads();

    // P4: unsorted bucket fill
    for (int j = tid; j < EDGES; j += 256) {
        int pos = atomicAdd(&fillc[s_e[j]], 1);
        id_u[pos] = (u16)j;
    }
    __syncthreads();

    // P5: rank within bucket -> sorted scatter (unique ids, exact rank)
    for (int j = tid; j < EDGES; j += 256) {
        int s = s_e[j];
        int lo = offs[s], hi = offs[s + 1];
        int rank = 0;
        for (int q = lo; q < hi; ++q) rank += (id_u[q] < j) ? 1 : 0;
        id_q[lo + rank] = (u16)j;
    }
    __syncthreads();

    // P6: gather weight/target into position order
    for (int q = tid; q < EDGES; q += 256) {
        int e = id_q[q];
        w_q[q] = ew[e];
        t_q[q] = t_e[e];
    }
    __syncthreads();

    // P7: first position in bucket(t) with id > my id
    for (int q = tid; q < EDGES; q += 256) {
        int myid = id_q[q];
        int t = t_q[q];
        int lo = offs[t], hi = offs[t + 1];
        const int hi0 = hi;
        while (lo < hi) {
            int mid = (lo + hi) >> 1;
            if (id_q[mid] > myid) hi = mid; else lo = mid + 1;
        }
        start_q[q] = (lo < hi0) ? (u16)lo : (u16)0xFFFFu;
    }
    __syncthreads();

    // P8: rho init (rho aliases s_e/t_e — both dead now)
    for (int q = tid; q < EDGES; q += 256) rho[q] = 1.0f;
    __syncthreads();

    // P9: Neumann passes
    for (int pass = 0; pass < 5; ++pass) {
        for (int q = tid; q < EDGES; q += 256) sfx[q] = w_q[q] * rho[q];
        __syncthreads();
        {   // per-bucket suffix sum (thread tid owns bucket tid)
            int lo = offs[tid], hi = offs[tid + 1];
            float run = 0.0f;
            for (int q = hi - 1; q >= lo; --q) { run += sfx[q]; sfx[q] = run; }
        }
        __syncthreads();
        for (int q = tid; q < EDGES; q += 256) {
            int st = start_q[q];
            rho[q] = 1.0f + ((st != 0xFFFF) ? sfx[st] : 0.0f);
        }
        __syncthreads();
    }

    // P10: r[n] = 1 + sum_bucket w*rho ; c = r/256
    {
        int lo = offs[tid], hi = offs[tid + 1];
        float acc = 0.0f;
        for (int q = lo; q < hi; ++q) acc += w_q[q] * rho[q];
        c_out[tid] = (1.0f + acc) * (1.0f / 256.0f);
    }
}

// ---------------------------------------------------------------------------
// K2: Wc[i,h] = sum_n c[n]*W[n,i,h] (rows 0..783); Wc[784,h] = sum_n c[n]*b[n,h].
// 4-way n-split, c staged in LDS, unroll 16 for deep load pipelining.
// Reads all of W exactly once (103 MB) — the structural HBM floor.
// ---------------------------------------------------------------------------
__global__ __launch_bounds__(256, 4) void k2_wc(const float* __restrict__ W,
                                                const float* __restrict__ bvec,
                                                const float* __restrict__ c,
                                                float* __restrict__ Wc) {
    const int bx = blockIdx.x;   // 0..98 (98 = bias row)
    const int p  = blockIdx.y;   // 0..3
    const int n0 = p * 64;
    __shared__ float cs[64];

    const int tid = threadIdx.x;
    if (tid < 64) cs[tid] = c[n0 + tid];
    __syncthreads();

    if (bx == 98) {
        if (tid < 32) {
            const float4* b4 = (const float4*)bvec;
            float4 acc = make_float4(0.f, 0.f, 0.f, 0.f);
            #pragma unroll 16
            for (int n = 0; n < 64; ++n) {
                float cn = cs[n];
                float4 v = b4[(n0 + n) * 32 + tid];
                acc.x += cn * v.x; acc.y += cn * v.y;
                acc.z += cn * v.z; acc.w += cn * v.w;
            }
            float* dst = Wc + 784 * 128 + tid * 4;
            atomicAdd(dst + 0, acc.x);
            atomicAdd(dst + 1, acc.y);
            atomicAdd(dst + 2, acc.z);
            atomicAdd(dst + 3, acc.w);
        }
        return;
    }

    const int j  = bx * 256 + tid;           // < 25088
    const int i  = j >> 5;                   // 0..783
    const int h4 = j & 31;                   // 0..31
    const float4* W4 = (const float4*)W + ((size_t)n0 * 784 + i) * 32 + h4;
    float4 acc = make_float4(0.f, 0.f, 0.f, 0.f);
    #pragma unroll 16
    for (int n = 0; n < 64; ++n) {
        float cn = cs[n];
        float4 v = W4[(size_t)n * (784 * 32)];
        acc.x += cn * v.x; acc.y += cn * v.y;
        acc.z += cn * v.z; acc.w += cn * v.w;
    }
    float* dst = Wc + i * 128 + h4 * 4;
    atomicAdd(dst + 0, acc.x);
    atomicAdd(dst + 1, acc.y);
    atomicAdd(dst + 2, acc.z);
    atomicAdd(dst + 3, acc.w);
}

// ---------------------------------------------------------------------------
// K3: out[b,h] = sum_i x[b,i]*Wc[i,h] + Wc[784,h].
// 64 blocks x 4 batch rows, full K per block -> direct stores, no atomics,
// no out-memset. Wc is L2-hot (just written by K2).
// ---------------------------------------------------------------------------
__global__ __launch_bounds__(256) void k3_gemm(const float* __restrict__ x,
                                               const float* __restrict__ Wc,
                                               float* __restrict__ out) {
    const int blk = blockIdx.x;              // 0..63 -> rows blk*4 .. blk*4+3
    __shared__ float xs[4 * 784];
    const int tid = threadIdx.x;

    const float4* x4  = (const float4*)(x + (size_t)blk * 4 * 784);
    float4*       xs4 = (float4*)xs;
    for (int idx = tid; idx < 4 * 196; idx += 256) xs4[idx] = x4[idx];
    __syncthreads();

    const int h    = tid & 127;
    const int half = tid >> 7;               // 0..1 -> rows half*2, half*2+1
    const float* xr0 = xs + (half * 2) * 784;
    const float* xr1 = xs + (half * 2 + 1) * 784;

    float a0 = 0.f, a1 = 0.f;
    #pragma unroll 8
    for (int i = 0; i < 784; ++i) {
        float wv = Wc[i * 128 + h];
        a0 += xr0[i] * wv;
        a1 += xr1[i] * wv;
    }
    float bch = Wc[784 * 128 + h];
    out[(size_t)(blk * 4 + half * 2) * 128 + h]     = a0 + bch;
    out[(size_t)(blk * 4 + half * 2 + 1) * 128 + h] = a1 + bch;
}

extern "C" void kernel_launch(void* const* d_in, const int* in_sizes, int n_in,
                              void* d_out, int out_size, void* d_ws, size_t ws_size,
                              hipStream_t stream) {
    const float* x  = (const float*)d_in[0];
    const float* W  = (const float*)d_in[1];
    const float* bv = (const float*)d_in[2];
    const int*   ei = (const int*)d_in[3];
    const float* ew = (const float*)d_in[4];
    float* out = (float*)d_out;

    float* c_ws = (float*)d_ws;                  // 256 floats
    float* Wc   = (float*)d_ws + 256;            // 785*128 floats (row 784 = bias)

    hipMemsetAsync(Wc, 0, (size_t)785 * 128 * sizeof(float), stream);
    k1_coeff<<<1, 256, 0, stream>>>(ei, ew, c_ws);
    k2_wc<<<dim3(99, 4), 256, 0, stream>>>(W, bv, c_ws, Wc);
    k3_gemm<<<64, 256, 0, stream>>>(x, Wc, out);
}

// Round 3
// 225.621 us; speedup vs baseline: 1.0504x; 1.0504x over previous
//
#include <hip/hip_runtime.h>

#define EDGES 4096
#define NNODES 256
// x: (256, 784), W: (256, 784, 128), b: (256, 128), edge_index: (2, 4096), ew: (4096)
// out: (256, 128)

typedef unsigned short u16;

// ---------------------------------------------------------------------------
// K1 (grid=33): block 0 computes c[n] = (1/N)*r[n] where
// r^T = 1^T * Prod_{e=E-1..0}(I + w_e E_{t,s});
//   rho_e = 1 + sum_{e'>e, s_{e'}=t_e} w_{e'} rho_{e'},  r[n] = 1 + sum_{s_e=n} w_e rho_e
// via 5 Neumann passes (L strictly triangular, ||L||~0.1 -> err ~1e-6).
// Blocks 1..32 zero the Wc accumulator (replaces a separate memset dispatch;
// runs concurrently with the serial solve on block 0).
// ---------------------------------------------------------------------------
__global__ __launch_bounds__(256) void k1_coeff(const int* __restrict__ ei,
                                                const float* __restrict__ ew,
                                                float* __restrict__ c_out,
                                                float* __restrict__ Wc) {
    if (blockIdx.x != 0) {
        // zero Wc: 785*128 floats = 25120 float4, 32 blocks x 785 float4
        float4* w4 = (float4*)Wc;
        int base = (blockIdx.x - 1) * 785;
        for (int t = threadIdx.x; t < 785; t += 256) {
            w4[base + t] = make_float4(0.f, 0.f, 0.f, 0.f);
        }
        return;
    }

    __shared__ __align__(16) char smem[59648];
    float* w_q    = (float*)(smem);              // [0, 16K)   weight per sorted position
    u16*   s_e    = (u16*)  (smem + 16384);      // [16K, 24K)
    u16*   t_e    = (u16*)  (smem + 24576);      // [24K, 32K)
    float* rho    = (float*)(smem + 16384);      // [16K, 32K) after P7 (aliases s_e/t_e)
    u16*   id_q   = (u16*)  (smem + 32768);      // [32K, 40K) sorted ids
    u16*   t_q    = (u16*)  (smem + 40960);      // [40K, 48K)
    float* sfx    = (float*)(smem + 32768);      // [32K, 48K) after P7
    u16*   id_u   = (u16*)  (smem + 49152);      // [48K, 56K)
    u16*   start_q= (u16*)  (smem + 49152);      // aliases id_u (dead by then)
    int*   offs   = (int*)  (smem + 57344);      // 257 ints
    int*   fillc  = (int*)  (smem + 58372);      // 256 ints

    const int tid = threadIdx.x;

    // P0: load edges, zero counters
    for (int j = tid; j < EDGES; j += 256) {
        s_e[j] = (u16)ei[j];
        t_e[j] = (u16)ei[EDGES + j];
    }
    fillc[tid] = 0;
    __syncthreads();

    // P1: count by source
    for (int j = tid; j < EDGES; j += 256) atomicAdd(&fillc[s_e[j]], 1);
    __syncthreads();

    // P2: exclusive scan via wave-0 shfl (lane l owns buckets 4l..4l+3)
    if (tid < 64) {
        int b0 = tid * 4;
        int c0 = fillc[b0], c1 = fillc[b0 + 1], c2 = fillc[b0 + 2], c3 = fillc[b0 + 3];
        int s  = c0 + c1 + c2 + c3;
        int inc = s;
        #pragma unroll
        for (int d = 1; d < 64; d <<= 1) {
            int v = __shfl_up(inc, d);
            if (tid >= d) inc += v;
        }
        int excl = inc - s;
        offs[b0]     = excl;
        offs[b0 + 1] = excl + c0;
        offs[b0 + 2] = excl + c0 + c1;
        offs[b0 + 3] = excl + c0 + c1 + c2;
        if (tid == 63) offs[256] = inc;
    }
    __syncthreads();

    // P3: fill cursors = offs
    fillc[tid] = offs[tid];
    __syncthreads();

    // P4: unsorted bucket fill
    for (int j = tid; j < EDGES; j += 256) {
        int pos = atomicAdd(&fillc[s_e[j]], 1);
        id_u[pos] = (u16)j;
    }
    __syncthreads();

    // P5: rank within bucket -> sorted scatter (unique ids, exact rank)
    for (int j = tid; j < EDGES; j += 256) {
        int s = s_e[j];
        int lo = offs[s], hi = offs[s + 1];
        int rank = 0;
        for (int q = lo; q < hi; ++q) rank += (id_u[q] < j) ? 1 : 0;
        id_q[lo + rank] = (u16)j;
    }
    __syncthreads();

    // P6: gather weight/target into position order
    for (int q = tid; q < EDGES; q += 256) {
        int e = id_q[q];
        w_q[q] = ew[e];
        t_q[q] = t_e[e];
    }
    __syncthreads();

    // P7: first position in bucket(t) with id > my id
    for (int q = tid; q < EDGES; q += 256) {
        int myid = id_q[q];
        int t = t_q[q];
        int lo = offs[t], hi = offs[t + 1];
        const int hi0 = hi;
        while (lo < hi) {
            int mid = (lo + hi) >> 1;
            if (id_q[mid] > myid) hi = mid; else lo = mid + 1;
        }
        start_q[q] = (lo < hi0) ? (u16)lo : (u16)0xFFFFu;
    }
    __syncthreads();

    // P8: rho init (rho aliases s_e/t_e — both dead now)
    for (int q = tid; q < EDGES; q += 256) rho[q] = 1.0f;
    __syncthreads();

    // P9: Neumann passes
    for (int pass = 0; pass < 5; ++pass) {
        for (int q = tid; q < EDGES; q += 256) sfx[q] = w_q[q] * rho[q];
        __syncthreads();
        {   // per-bucket suffix sum (thread tid owns bucket tid)
            int lo = offs[tid], hi = offs[tid + 1];
            float run = 0.0f;
            for (int q = hi - 1; q >= lo; --q) { run += sfx[q]; sfx[q] = run; }
        }
        __syncthreads();
        for (int q = tid; q < EDGES; q += 256) {
            int st = start_q[q];
            rho[q] = 1.0f + ((st != 0xFFFF) ? sfx[st] : 0.0f);
        }
        __syncthreads();
    }

    // P10: r[n] = 1 + sum_bucket w*rho ; c = r/256
    {
        int lo = offs[tid], hi = offs[tid + 1];
        float acc = 0.0f;
        for (int q = lo; q < hi; ++q) acc += w_q[q] * rho[q];
        c_out[tid] = (1.0f + acc) * (1.0f / 256.0f);
    }
}

// ---------------------------------------------------------------------------
// K2: Wc[i,h] = sum_n c[n]*W[n,i,h] (rows 0..783); Wc[784,h] = sum_n c[n]*b[n,h].
// 8-way n-split (grid 99x8 = 792 blocks ~ 3 resident/CU for tail smoothing),
// c staged in LDS, unroll 8. Reads all of W exactly once (103 MB) — the
// structural HBM floor (~16 us at 6.3 TB/s).
// ---------------------------------------------------------------------------
__global__ __launch_bounds__(256, 4) void k2_wc(const float* __restrict__ W,
                                                const float* __restrict__ bvec,
                                                const float* __restrict__ c,
                                                float* __restrict__ Wc) {
    const int bx = blockIdx.x;   // 0..98 (98 = bias row)
    const int p  = blockIdx.y;   // 0..7
    const int n0 = p * 32;
    __shared__ float cs[32];

    const int tid = threadIdx.x;
    if (tid < 32) cs[tid] = c[n0 + tid];
    __syncthreads();

    if (bx == 98) {
        if (tid < 32) {
            const float4* b4 = (const float4*)bvec;
            float4 acc = make_float4(0.f, 0.f, 0.f, 0.f);
            #pragma unroll 8
            for (int n = 0; n < 32; ++n) {
                float cn = cs[n];
                float4 v = b4[(n0 + n) * 32 + tid];
                acc.x += cn * v.x; acc.y += cn * v.y;
                acc.z += cn * v.z; acc.w += cn * v.w;
            }
            float* dst = Wc + 784 * 128 + tid * 4;
            atomicAdd(dst + 0, acc.x);
            atomicAdd(dst + 1, acc.y);
            atomicAdd(dst + 2, acc.z);
            atomicAdd(dst + 3, acc.w);
        }
        return;
    }

    const int j  = bx * 256 + tid;           // < 25088
    const int i  = j >> 5;                   // 0..783
    const int h4 = j & 31;                   // 0..31
    const float4* W4 = (const float4*)W + ((size_t)n0 * 784 + i) * 32 + h4;
    float4 acc = make_float4(0.f, 0.f, 0.f, 0.f);
    #pragma unroll 8
    for (int n = 0; n < 32; ++n) {
        float cn = cs[n];
        float4 v = W4[(size_t)n * (784 * 32)];
        acc.x += cn * v.x; acc.y += cn * v.y;
        acc.z += cn * v.z; acc.w += cn * v.w;
    }
    float* dst = Wc + i * 128 + h4 * 4;
    atomicAdd(dst + 0, acc.x);
    atomicAdd(dst + 1, acc.y);
    atomicAdd(dst + 2, acc.z);
    atomicAdd(dst + 3, acc.w);
}

// ---------------------------------------------------------------------------
// K3: out[b,h] = sum_i x[b,i]*Wc[i,h] + Wc[784,h].
// 128 blocks x 2 batch rows, full K per block -> direct stores, no atomics.
// Wc (401 KB) is L2-hot from K2. 4 ILP accumulators per thread.
// ---------------------------------------------------------------------------
__global__ __launch_bounds__(256) void k3_gemm(const float* __restrict__ x,
                                               const float* __restrict__ Wc,
                                               float* __restrict__ out) {
    const int blk = blockIdx.x;              // 0..127 -> rows 2*blk, 2*blk+1
    __shared__ float xs[2 * 784];
    const int tid = threadIdx.x;

    const float4* x4  = (const float4*)(x + (size_t)blk * 2 * 784);
    float4*       xs4 = (float4*)xs;
    for (int idx = tid; idx < 2 * 196; idx += 256) xs4[idx] = x4[idx];
    __syncthreads();

    const int h = tid & 127;
    const int r = tid >> 7;                  // 0..1
    const float* xr = xs + r * 784;

    float a0 = 0.f, a1 = 0.f, a2 = 0.f, a3 = 0.f;
    #pragma unroll 4
    for (int ii = 0; ii < 196; ++ii) {
        const int i = ii * 4;
        a0 += xr[i + 0] * Wc[(i + 0) * 128 + h];
        a1 += xr[i + 1] * Wc[(i + 1) * 128 + h];
        a2 += xr[i + 2] * Wc[(i + 2) * 128 + h];
        a3 += xr[i + 3] * Wc[(i + 3) * 128 + h];
    }
    float bch = Wc[784 * 128 + h];
    out[(size_t)(blk * 2 + r) * 128 + h] = (a0 + a1) + (a2 + a3) + bch;
}

extern "C" void kernel_launch(void* const* d_in, const int* in_sizes, int n_in,
                              void* d_out, int out_size, void* d_ws, size_t ws_size,
                              hipStream_t stream) {
    const float* x  = (const float*)d_in[0];
    const float* W  = (const float*)d_in[1];
    const float* bv = (const float*)d_in[2];
    const int*   ei = (const int*)d_in[3];
    const float* ew = (const float*)d_in[4];
    float* out = (float*)d_out;

    float* c_ws = (float*)d_ws;                  // 256 floats
    float* Wc   = (float*)d_ws + 256;            // 785*128 floats (row 784 = bias)

    k1_coeff<<<33, 256, 0, stream>>>(ei, ew, c_ws, Wc);
    k2_wc<<<dim3(99, 8), 256, 0, stream>>>(W, bv, c_ws, Wc);
    k3_gemm<<<128, 256, 0, stream>>>(x, Wc, out);
}